// Round 13
// baseline (264.326 us; speedup 1.0000x reference)
//
#include <hip/hip_runtime.h>
#include <hip/hip_bf16.h>

#define HID 768
#define NHEAD 12
#define DKH 64
#define BSZ 4
#define SEQ 2048
#define MTOT (BSZ*SEQ)   // 8192
#define NBH (BSZ*NHEAD)  // 48

typedef __attribute__((ext_vector_type(8))) short   s16x8;   // raw 8x bf16 storage
typedef __attribute__((ext_vector_type(8))) __bf16  bf16x8;  // MFMA operand
typedef __attribute__((ext_vector_type(4))) __bf16  bf16x4;
typedef __attribute__((ext_vector_type(4))) float   f32x4;

#define MFMA16x32(A,B,C) __builtin_amdgcn_mfma_f32_16x16x32_bf16((A),(B),(C),0,0,0)

__device__ __forceinline__ unsigned short f2bf(float f) {
  union { float f; unsigned int u; } a; a.f = f;
  return (unsigned short)((a.u + 0x7FFFu + ((a.u >> 16) & 1u)) >> 16);  // RNE, finite inputs
}

__device__ __forceinline__ void gload_lds16(const unsigned short* g, unsigned short* l) {
  __builtin_amdgcn_global_load_lds((const __attribute__((address_space(1))) void*)g,
                                   (__attribute__((address_space(3))) void*)l, 16, 0, 0);
}

// x + all four weight matrices in ONE launch.
__global__ __launch_bounds__(256) void cvtall_kernel(const float* __restrict__ x,
                                                     const float* __restrict__ w0,
                                                     const float* __restrict__ w1,
                                                     const float* __restrict__ w2,
                                                     const float* __restrict__ w3,
                                                     unsigned short* __restrict__ xb,
                                                     unsigned short* __restrict__ wb) {
  const int bid = blockIdx.x;
  const float* src; unsigned short* dst; int off;
  if (bid < 6144) {
    src = x; dst = xb; off = bid * 1024;
  } else {
    const int t = bid - 6144;
    const int wi = t / 576;              // 576 blocks per 768x768 matrix
    const int ro = t - wi * 576;
    src = (wi == 0) ? w0 : (wi == 1) ? w1 : (wi == 2) ? w2 : w3;
    dst = wb + (size_t)wi * HID * HID;
    off = ro * 1024;
  }
  const int i = off + threadIdx.x * 4;
  float4 v = *(const float4*)(src + i);
  ushort4 o;
  o.x = f2bf(v.x); o.y = f2bf(v.y); o.z = f2bf(v.z); o.w = f2bf(v.w);
  *(ushort4*)(dst + i) = o;
}

// ---------------- gemm<0>: 3-deep pipeline, counted vmcnt (round-12) -------
#define VM4 asm volatile("s_waitcnt vmcnt(4)" ::: "memory")
#define VM0 asm volatile("s_waitcnt vmcnt(0)" ::: "memory")
#define CFENCE asm volatile("" ::: "memory")

#define G0_STAGE(BUF, KTN)                                                  \
    _Pragma("unroll")                                                       \
    for (int i = 0; i < 2; ++i) {                                           \
      const int c = wave * 2 + i;                                           \
      gload_lds16(Aptr + (size_t)(c*16 + sr4) * HID + (KTN) + sc4,          \
                  As[BUF] + c*512);                                         \
      gload_lds16(Wptr + (size_t)(c*16 + sr4) * HID + (KTN) + sc4,          \
                  Bs[BUF] + c*512);                                         \
    }

#define G0_COMPUTE(BUF)                                                     \
    {                                                                       \
      const char* ab = (const char*)As[BUF];                                \
      const char* bb = (const char*)Bs[BUF];                                \
      bf16x8 af[4], bfr[4];                                                 \
      _Pragma("unroll")                                                     \
      for (int mb = 0; mb < 4; ++mb) {                                      \
        const int r = wm + mb*16 + l16;                                     \
        af[mb] = *(const bf16x8*)(ab + r*64 + (((lg) ^ (r & 3)) << 4));     \
      }                                                                     \
      _Pragma("unroll")                                                     \
      for (int nb = 0; nb < 4; ++nb) {                                      \
        const int r = wn + nb*16 + l16;                                     \
        bfr[nb] = *(const bf16x8*)(bb + r*64 + (((lg) ^ (r & 3)) << 4));    \
      }                                                                     \
      _Pragma("unroll")                                                     \
      for (int mb = 0; mb < 4; ++mb)                                        \
        _Pragma("unroll")                                                   \
        for (int nb = 0; nb < 4; ++nb)                                      \
          acc[mb][nb] = MFMA16x32(af[mb], bfr[nb], acc[mb][nb]);            \
    }

#define G0_STEP(BUF, KTN, PF)                                               \
  {                                                                         \
    if (PF) { G0_STAGE(((BUF)+2)%3, KTN) }                                  \
    G0_COMPUTE(BUF)                                                         \
    if (PF) { VM4; } else { VM0; }                                          \
    __builtin_amdgcn_sched_barrier(0);                                      \
    __builtin_amdgcn_s_barrier();                                           \
    CFENCE;                                                                 \
  }

__global__ __launch_bounds__(256, 3) void gemm0_kernel(
    const unsigned short* __restrict__ A,
    const unsigned short* __restrict__ W,
    const float* __restrict__ bias0,
    const float* __restrict__ bias1,
    const float* __restrict__ bias2,
    unsigned short* __restrict__ out,
    unsigned short* __restrict__ vtimg)
{
  __shared__ unsigned short As[3][128*32];
  __shared__ unsigned short Bs[3][128*32];
  const int tid  = threadIdx.x;
  const int wave = tid >> 6, lane = tid & 63;
  const int l16  = lane & 15, lg = lane >> 4;
  const int f    = blockIdx.x;
  const int xcd  = f & 7, rr = f >> 3;
  const int bx   = xcd*8 + (rr & 7), by = rr >> 3;
  const int m0   = bx * 128, n0 = by * 128;
  const int wm   = (wave & 1) * 64,  wn = (wave >> 1) * 64;

  const f32x4 z4 = {0.f, 0.f, 0.f, 0.f};
  f32x4 acc[4][4];
#pragma unroll
  for (int i = 0; i < 4; ++i)
#pragma unroll
    for (int j = 0; j < 4; ++j) acc[i][j] = z4;

  const int sr4 = lane >> 2;                     // row within 16-row chunk
  const int sc4 = ((lane & 3) ^ (sr4 & 3)) << 3; // inverse-swizzled col (elems)
  const unsigned short* Aptr = A + (size_t)m0 * HID;
  const unsigned short* Wptr = W + (size_t)n0 * HID;

  // prologue: stage k0 -> buf0, k32 -> buf1; drain buf0 only
  G0_STAGE(0, 0)
  G0_STAGE(1, 32)
  VM4;
  __builtin_amdgcn_sched_barrier(0);
  __builtin_amdgcn_s_barrier();
  CFENCE;

#pragma unroll 1
  for (int tt = 0; tt < 7; ++tt) {               // steps s=0..20
    G0_STEP(0, (tt*3+2)*32, 1)
    G0_STEP(1, (tt*3+3)*32, 1)
    G0_STEP(2, (tt*3+4)*32, 1)
  }
  G0_STEP(0, 23*32, 1)                           // s=21, stage k736
  G0_STEP(1, 0, 0)                               // s=22, drain all
  G0_COMPUTE(2)                                  // s=23, compute only

  // epilogue
  const float QSCALE = 0.18033688011112042f;     // 0.125 * log2(e) folded into q
  const int which = (n0 + wn) / HID;             // uniform per wave
  if (which == 2) {
    // V: write directly into LINEAR Vt image [bh][tile][d][kcol]
    const int h = (n0 + wn - 2*HID) >> 6;
#pragma unroll
    for (int nb = 0; nb < 4; ++nb) {
      const int d = nb*16 + l16;
      const float bias = bias2[h*64 + d];
#pragma unroll
      for (int mb = 0; mb < 4; ++mb) {
        const int m    = m0 + wm + mb*16 + lg*4;
        const int b    = m >> 11, s = m & (SEQ - 1);
        const int tile = s >> 6;
        const int slot = (s & 63) >> 2;          // linear (global has no banks)
        ushort4 w;
        w.x = f2bf(acc[mb][nb][0] + bias);
        w.y = f2bf(acc[mb][nb][1] + bias);
        w.z = f2bf(acc[mb][nb][2] + bias);
        w.w = f2bf(acc[mb][nb][3] + bias);
        *(ushort4*)(vtimg + ((((size_t)(b*NHEAD + h)*32 + tile)*64 + d)*64 + slot*4)) = w;
      }
    }
  } else {
    const float* bp  = (which == 0) ? bias0 : bias1;
    const float scl  = (which == 0) ? QSCALE : 1.0f;
    const int e_base = n0 + wn - which*HID;
#pragma unroll
    for (int nb = 0; nb < 4; ++nb) {
      const int e = e_base + nb*16 + l16;
      const float bias = bp[e];
      const int h = e >> 6, d = e & 63;
#pragma unroll
      for (int mb = 0; mb < 4; ++mb)
#pragma unroll
        for (int j = 0; j < 4; ++j) {
          const int m = m0 + wm + mb*16 + lg*4 + j;
          const int b = m >> 11, s = m & (SEQ - 1);
          const float v = (acc[mb][nb][j] + bias) * scl;
          out[((((size_t)which*BSZ + b)*NHEAD + h)*SEQ + s)*DKH + d] = f2bf(v);
        }
    }
  }
}

// ---------------- gemm<1>: round-11 measured config (NB=2, BK=64, dbuf) ----
#define GEMM_STEP(CUR, KTN, DOPREF)                                         \
  {                                                                         \
    if (DOPREF) {                                                           \
      _Pragma("unroll")                                                     \
      for (int i = 0; i < 4; ++i) {                                         \
        const int c = wave * 4 + i;                                         \
        gload_lds16(Aptr + (size_t)(c*8 + sr) * HID + (KTN) + sc8,          \
                    As[(CUR)^1] + c*512);                                   \
      }                                                                     \
      _Pragma("unroll")                                                     \
      for (int i = 0; i < 2; ++i) {                                         \
        const int c = wave * 2 + i;                                         \
        gload_lds16(Wptr + (size_t)(c*8 + sr) * HID + (KTN) + sc8,          \
                    Bs[(CUR)^1] + c*512);                                   \
      }                                                                     \
    }                                                                       \
    const char* ab = (const char*)As[CUR];                                  \
    const char* bb = (const char*)Bs[CUR];                                  \
    _Pragma("unroll")                                                       \
    for (int kk = 0; kk < 2; ++kk) {                                        \
      bf16x8 af[4], bfr[2];                                                 \
      _Pragma("unroll")                                                     \
      for (int mb = 0; mb < 4; ++mb) {                                      \
        const int r = wm + mb*16 + l16;                                     \
        af[mb] = *(const bf16x8*)(ab + r*128 + (((kk*4 + lg) ^ (l16 & 7)) << 4)); \
      }                                                                     \
      _Pragma("unroll")                                                     \
      for (int nb = 0; nb < 2; ++nb) {                                      \
        const int r = wn + nb*16 + l16;                                     \
        bfr[nb] = *(const bf16x8*)(bb + r*128 + (((kk*4 + lg) ^ (l16 & 7)) << 4)); \
      }                                                                     \
      _Pragma("unroll")                                                     \
      for (int mb = 0; mb < 4; ++mb)                                        \
        _Pragma("unroll")                                                   \
        for (int nb = 0; nb < 2; ++nb)                                      \
          acc[mb][nb] = MFMA16x32(af[mb], bfr[nb], acc[mb][nb]);            \
    }                                                                       \
    __syncthreads();                                                        \
  }

__global__ __launch_bounds__(256) void gemm1_kernel(
    const unsigned short* __restrict__ A,
    const unsigned short* __restrict__ W,
    const float* __restrict__ bias0,
    float* __restrict__ out)
{
  __shared__ unsigned short As[2][128*64];
  __shared__ unsigned short Bs[2][64*64];
  const int tid  = threadIdx.x;
  const int wave = tid >> 6, lane = tid & 63;
  const int l16  = lane & 15, lg = lane >> 4;
  const int f    = blockIdx.x;
  const int xcd  = f & 7, rr = f >> 3;
  const int bx   = xcd*8 + (rr & 7), by = rr >> 3;
  const int m0   = bx * 128, n0 = by * 64;
  const int wm   = (wave & 1) * 64,  wn = (wave >> 1) * 32;

  const f32x4 z4 = {0.f, 0.f, 0.f, 0.f};
  f32x4 acc[4][2];
#pragma unroll
  for (int i = 0; i < 4; ++i)
#pragma unroll
    for (int j = 0; j < 2; ++j) acc[i][j] = z4;

  const int sr  = lane >> 3;
  const int sc8 = ((lane & 7) ^ sr) << 3;
  const unsigned short* Aptr = A + (size_t)m0 * HID;
  const unsigned short* Wptr = W + (size_t)n0 * HID;

#pragma unroll
  for (int i = 0; i < 4; ++i) {
    const int c = wave * 4 + i;
    gload_lds16(Aptr + (size_t)(c*8 + sr) * HID + sc8, As[0] + c*512);
  }
#pragma unroll
  for (int i = 0; i < 2; ++i) {
    const int c = wave * 2 + i;
    gload_lds16(Wptr + (size_t)(c*8 + sr) * HID + sc8, Bs[0] + c*512);
  }
  __syncthreads();

#pragma unroll 1
  for (int tt = 0; tt < 6; ++tt) {
    GEMM_STEP(0, (2*tt+1)*64, true)
    GEMM_STEP(1, (2*tt+2)*64, (tt < 5))
  }

#pragma unroll
  for (int nb = 0; nb < 2; ++nb) {
    const int n = n0 + wn + nb*16 + l16;
    const float bias = bias0[n];
#pragma unroll
    for (int mb = 0; mb < 4; ++mb)
#pragma unroll
      for (int j = 0; j < 4; ++j) {
        const int m = m0 + wm + mb*16 + lg*4 + j;
        out[(size_t)m*HID + n] = acc[mb][nb][j] + bias;
      }
  }
}

// Flash attention v7: V never touches LDS (m169: V is L2-resident; T14:
// reg-prefetch one step ahead). K keeps the proven LDS dbuf + 16B-XOR path.
// Per step: issue V(t+1) 16x global b64 + K(t+1) 2x gload_lds, compute
// QK(t) / softmax / PV(t) from V regs loaded at t-1, one barrier.
// V-image is LINEAR [bh][tile][d][kcol] (global: no bank conflicts).
#define VLOAD(VS, VP)                                                       \
    _Pragma("unroll")                                                       \
    for (int db = 0; db < 4; ++db) {                                        \
      VS[db][0] = *(const bf16x4*)((VP) + db*1024);                         \
      VS[db][1] = *(const bf16x4*)((VP) + db*1024 + 16);                    \
      VS[db][2] = *(const bf16x4*)((VP) + db*1024 + 32);                    \
      VS[db][3] = *(const bf16x4*)((VP) + db*1024 + 48);                    \
    }

#define ATTN_STEP(CUR, VCUR, VNXT, DOPREF)                                  \
  {                                                                         \
    if (DOPREF) {                                                           \
      VLOAD(VNXT, vPtr)                                                     \
      vPtr += 4096;                                                         \
      gload_lds16(kSrc0, Ks[(CUR)^1] + wave*1024);                          \
      gload_lds16(kSrc1, Ks[(CUR)^1] + wave*1024 + 512);                    \
      kSrc0 += 64*DKH; kSrc1 += 64*DKH;                                     \
    }                                                                       \
    const char* kb = (const char*)Ks[CUR];                                  \
    f32x4 sc[2][4];                                                         \
    __builtin_amdgcn_s_setprio(1);                                          \
    _Pragma("unroll")                                                       \
    for (int nb = 0; nb < 4; ++nb) {                                        \
      bf16x8 kf0 = *(const bf16x8*)(kb + kbase0 + nb*2048);                 \
      bf16x8 kf1 = *(const bf16x8*)(kb + kbase1 + nb*2048);                 \
      f32x4 z0 = z4, z1 = z4;                                               \
      z0 = MFMA16x32(kf0, qf[0][0], z0);                                    \
      z0 = MFMA16x32(kf1, qf[0][1], z0);                                    \
      z1 = MFMA16x32(kf0, qf[1][0], z1);                                    \
      z1 = MFMA16x32(kf1, qf[1][1], z1);                                    \
      sc[0][nb] = z0; sc[1][nb] = z1;                                       \
    }                                                                       \
    __builtin_amdgcn_s_setprio(0);                                          \
    bf16x8 pa[2][2];                                                        \
    _Pragma("unroll")                                                       \
    for (int qa = 0; qa < 2; ++qa)                                          \
      _Pragma("unroll")                                                     \
      for (int nb = 0; nb < 4; ++nb)                                        \
        _Pragma("unroll")                                                   \
        for (int j = 0; j < 4; ++j)                                         \
          pa[qa][nb>>1][(nb&1)*4 + j] =                                     \
            (__bf16)__builtin_amdgcn_exp2f(sc[qa][nb][j]);                  \
    __builtin_amdgcn_s_setprio(1);                                          \
    csum[0] = MFMA16x32(pa[0][0], ones, csum[0]);                           \
    csum[0] = MFMA16x32(pa[0][1], ones, csum[0]);                           \
    csum[1] = MFMA16x32(pa[1][0], ones, csum[1]);                           \
    csum[1] = MFMA16x32(pa[1][1], ones, csum[1]);                           \
    _Pragma("unroll")                                                       \
    for (int db = 0; db < 4; ++db) {                                        \
      bf16x8 vf0 = __builtin_shufflevector(VCUR[db][0], VCUR[db][1],        \
                                           0,1,2,3,4,5,6,7);                \
      bf16x8 vf1 = __builtin_shufflevector(VCUR[db][2], VCUR[db][3],        \
                                           0,1,2,3,4,5,6,7);                \
      cacc[0][db] = MFMA16x32(pa[0][0], vf0, cacc[0][db]);                  \
      cacc[0][db] = MFMA16x32(pa[0][1], vf1, cacc[0][db]);                  \
      cacc[1][db] = MFMA16x32(pa[1][0], vf0, cacc[1][db]);                  \
      cacc[1][db] = MFMA16x32(pa[1][1], vf1, cacc[1][db]);                  \
    }                                                                       \
    __builtin_amdgcn_s_setprio(0);                                          \
    __syncthreads();                                                        \
  }

__global__ __launch_bounds__(256, 3) void attn_kernel(const unsigned short* __restrict__ qkv,
                                                      const unsigned short* __restrict__ vtimg,
                                                      unsigned short* __restrict__ ctx)
{
  __shared__ unsigned short Ks[2][64*64];     // K only: [kc][d] 16B-XOR-swizzled
  const int tid  = threadIdx.x;
  const int wave = tid >> 6, lane = tid & 63;
  const int l16  = lane & 15, lg = lane >> 4;
  const int f   = blockIdx.x;
  const int xcd = f & 7, idx = f >> 3;        // idx 0..95
  const int bh  = xcd * 6 + (idx >> 4);
  const int qt  = idx & 15;
  const int b   = bh / NHEAD, h = bh - b * NHEAD;
  const int q0  = qt * 128 + wave * 32;

  const unsigned short* Qg = qkv + (size_t)bh * (SEQ*DKH);
  const unsigned short* Kg = qkv + (size_t)(NBH + bh) * (SEQ*DKH);

  // K staging sources (inverse-16B-XOR pre-swizzled)
  const int srow  = lane >> 3;
  const int scolK = ((lane & 7) ^ srow) << 3;
  const unsigned short* kSrc0 = Kg + (size_t)(wave*16 + srow) * DKH + scolK;
  const unsigned short* kSrc1 = Kg + (size_t)(wave*16 + 8 + srow) * DKH + scolK;

  // per-lane V global pointer: element (d=db*16+l16, k=4lg..) in tile image
  const unsigned short* vPtr = vtimg + (size_t)bh*32*4096 + l16*64 + lg*4;

  // hoisted K swizzled LDS byte bases (loop-invariant)
  const int kbase0 = l16*128 + ((lg ^ (l16 & 7)) << 4);
  const int kbase1 = l16*128 + (((lg + 4) ^ (l16 & 7)) << 4);

  // Q B-fragments (registers for whole kernel)
  bf16x8 qf[2][2];
#pragma unroll
  for (int qa = 0; qa < 2; ++qa) {
    qf[qa][0] = *(const bf16x8*)(Qg + (size_t)(q0 + qa*16 + l16)*DKH + lg*8);
    qf[qa][1] = *(const bf16x8*)(Qg + (size_t)(q0 + qa*16 + l16)*DKH + 32 + lg*8);
  }

  bf16x8 ones;
#pragma unroll
  for (int e = 0; e < 8; ++e) ones[e] = (__bf16)1.0f;

  const f32x4 z4 = {0.f,0.f,0.f,0.f};
  f32x4 cacc[2][4];
  f32x4 csum[2] = {z4, z4};
#pragma unroll
  for (int qa = 0; qa < 2; ++qa)
#pragma unroll
    for (int db = 0; db < 4; ++db) cacc[qa][db] = z4;

  bf16x4 va[4][4], vb[4][4];                  // two V reg sets (T14 dbuf)

  // prologue: V(0) -> va regs; K(0) -> LDS buf0
  VLOAD(va, vPtr)
  vPtr += 4096;
  gload_lds16(kSrc0, Ks[0] + wave*1024);
  gload_lds16(kSrc1, Ks[0] + wave*1024 + 512);
  kSrc0 += 64*DKH; kSrc1 += 64*DKH;
  __syncthreads();

#pragma unroll 1
  for (int tt = 0; tt < 16; ++tt) {
    ATTN_STEP(0, va, vb, true)
    ATTN_STEP(1, vb, va, (tt < 15))
  }

  // epilogue: cacc row q=lg*4+j (same lane holds csum for that q) col d=db*16+l16
#pragma unroll
  for (int qa = 0; qa < 2; ++qa) {
    f32x4 inv;
#pragma unroll
    for (int j = 0; j < 4; ++j) inv[j] = 1.0f / csum[qa][j];
#pragma unroll
    for (int db = 0; db < 4; ++db)
#pragma unroll
      for (int j = 0; j < 4; ++j) {
        const int srow2 = q0 + qa*16 + lg*4 + j;
        ctx[((size_t)(b*SEQ + srow2))*HID + h*DKH + db*16 + l16] = f2bf(cacc[qa][db][j] * inv[j]);
      }
  }
}

extern "C" void kernel_launch(void* const* d_in, const int* in_sizes, int n_in,
                              void* d_out, int out_size, void* d_ws, size_t ws_size,
                              hipStream_t stream) {
  (void)in_sizes; (void)n_in; (void)out_size; (void)ws_size;
  const float* x  = (const float*)d_in[0];
  const float* Wq = (const float*)d_in[1];
  const float* bq = (const float*)d_in[2];
  const float* Wk = (const float*)d_in[3];
  const float* bk = (const float*)d_in[4];
  const float* Wv = (const float*)d_in[5];
  const float* bv = (const float*)d_in[6];
  const float* Wo = (const float*)d_in[7];
  const float* bo = (const float*)d_in[8];

  // workspace layout (bf16 elements): ~55 MB total
  unsigned short* ws   = (unsigned short*)d_ws;
  unsigned short* Xb   = ws;                                   // [8192][768]
  unsigned short* Wqkv = Xb + (size_t)MTOT * HID;              // [2304][768]
  unsigned short* Wob  = Wqkv + (size_t)3 * HID * HID;         // [768][768]
  unsigned short* qkvb = Wob + (size_t)HID * HID;              // [2][48][2048][64] (q,k only)
  unsigned short* vtb  = qkvb + (size_t)2 * NBH * SEQ * DKH;   // [48][32][64][64] linear V image
  unsigned short* ctxb = Xb;                                   // reuse after QKV GEMM

  cvtall_kernel<<<6144 + 4*576, 256, 0, stream>>>(x, Wq, Wk, Wv, Wo, Xb, Wqkv);

  gemm0_kernel<<<1152, 256, 0, stream>>>(Xb, Wqkv, bq, bk, bv, qkvb, vtb);
  attn_kernel<<<768, 256, 0, stream>>>(qkvb, vtb, ctxb);
  gemm1_kernel<<<768, 256, 0, stream>>>(ctxb, Wob, bo, (float*)d_out);
}

// Round 14
// 118.461 us; speedup vs baseline: 2.2313x; 2.2313x over previous
//
#include <hip/hip_runtime.h>
#include <hip/hip_bf16.h>

#define HID 768
#define NHEAD 12
#define DKH 64
#define BSZ 4
#define SEQ 2048
#define MTOT (BSZ*SEQ)   // 8192
#define NBH (BSZ*NHEAD)  // 48

typedef __attribute__((ext_vector_type(8))) short   s16x8;   // raw 8x bf16 storage
typedef __attribute__((ext_vector_type(8))) __bf16  bf16x8;  // MFMA operand
typedef __attribute__((ext_vector_type(4))) __bf16  bf16x4;
typedef __attribute__((ext_vector_type(4))) float   f32x4;

#define MFMA16x32(A,B,C) __builtin_amdgcn_mfma_f32_16x16x32_bf16((A),(B),(C),0,0,0)

__device__ __forceinline__ unsigned short f2bf(float f) {
  union { float f; unsigned int u; } a; a.f = f;
  return (unsigned short)((a.u + 0x7FFFu + ((a.u >> 16) & 1u)) >> 16);  // RNE, finite inputs
}

__device__ __forceinline__ void gload_lds16(const unsigned short* g, unsigned short* l) {
  __builtin_amdgcn_global_load_lds((const __attribute__((address_space(1))) void*)g,
                                   (__attribute__((address_space(3))) void*)l, 16, 0, 0);
}

// x + all four weight matrices in ONE launch.
__global__ __launch_bounds__(256) void cvtall_kernel(const float* __restrict__ x,
                                                     const float* __restrict__ w0,
                                                     const float* __restrict__ w1,
                                                     const float* __restrict__ w2,
                                                     const float* __restrict__ w3,
                                                     unsigned short* __restrict__ xb,
                                                     unsigned short* __restrict__ wb) {
  const int bid = blockIdx.x;
  const float* src; unsigned short* dst; int off;
  if (bid < 6144) {
    src = x; dst = xb; off = bid * 1024;
  } else {
    const int t = bid - 6144;
    const int wi = t / 576;              // 576 blocks per 768x768 matrix
    const int ro = t - wi * 576;
    src = (wi == 0) ? w0 : (wi == 1) ? w1 : (wi == 2) ? w2 : w3;
    dst = wb + (size_t)wi * HID * HID;
    off = ro * 1024;
  }
  const int i = off + threadIdx.x * 4;
  float4 v = *(const float4*)(src + i);
  ushort4 o;
  o.x = f2bf(v.x); o.y = f2bf(v.y); o.z = f2bf(v.z); o.w = f2bf(v.w);
  *(ushort4*)(dst + i) = o;
}

// C[m][n] = sum_k A[m][k] * W[n][k]   (A:[8192][768] bf16, W:[N][768] bf16)
// Tile 128 x (NB*32); BK=64; 16B-XOR-swizzled LDS; DOUBLE-BUFFERED
// single-barrier K-loop (stage t+1 before compute t). XCD-aware m-stripes.
// NB=2: 48KB LDS -> 3 blocks/CU (gemm1's proven config, now also for gemm0).
// MODE 0: N=2304, grid 2304 = 8 xcd x 8 m x 36 n; q/k scatter + bias
//         (+q-scale); V -> swizzled Vt image (per-element h/d: 32-col spans).
// MODE 1: N=768, grid 768 = 8 xcd x 8 m x 12 n; bias; FP32 out.
#define GEMM_STEP(CUR, KTN, DOPREF)                                         \
  {                                                                         \
    if (DOPREF) {                                                           \
      _Pragma("unroll")                                                     \
      for (int i = 0; i < 4; ++i) {                                         \
        const int c = wave * 4 + i;                                         \
        gload_lds16(Aptr + (size_t)(c*8 + sr) * HID + (KTN) + sc8,          \
                    As[(CUR)^1] + c*512);                                   \
      }                                                                     \
      _Pragma("unroll")                                                     \
      for (int i = 0; i < NB; ++i) {                                        \
        const int c = wave * NB + i;                                        \
        gload_lds16(Wptr + (size_t)(c*8 + sr) * HID + (KTN) + sc8,          \
                    Bs[(CUR)^1] + c*512);                                   \
      }                                                                     \
    }                                                                       \
    const char* ab = (const char*)As[CUR];                                  \
    const char* bb = (const char*)Bs[CUR];                                  \
    _Pragma("unroll")                                                       \
    for (int kk = 0; kk < 2; ++kk) {                                        \
      bf16x8 af[4], bfr[NB];                                                \
      _Pragma("unroll")                                                     \
      for (int mb = 0; mb < 4; ++mb) {                                      \
        const int r = wm + mb*16 + l16;                                     \
        af[mb] = *(const bf16x8*)(ab + r*128 + (((kk*4 + lg) ^ (l16 & 7)) << 4)); \
      }                                                                     \
      _Pragma("unroll")                                                     \
      for (int nb = 0; nb < NB; ++nb) {                                     \
        const int r = wn + nb*16 + l16;                                     \
        bfr[nb] = *(const bf16x8*)(bb + r*128 + (((kk*4 + lg) ^ (l16 & 7)) << 4)); \
      }                                                                     \
      _Pragma("unroll")                                                     \
      for (int mb = 0; mb < 4; ++mb)                                        \
        _Pragma("unroll")                                                   \
        for (int nb = 0; nb < NB; ++nb)                                     \
          acc[mb][nb] = MFMA16x32(af[mb], bfr[nb], acc[mb][nb]);            \
    }                                                                       \
    __syncthreads();                                                        \
  }

template<int MODE, int NB>
__global__ __launch_bounds__(256) void gemm_kernel(
    const unsigned short* __restrict__ A,
    const unsigned short* __restrict__ W,
    const float* __restrict__ bias0,
    const float* __restrict__ bias1,
    const float* __restrict__ bias2,
    void* __restrict__ out_raw,
    unsigned short* __restrict__ vtimg)
{
  __shared__ unsigned short As[2][128*64];
  __shared__ unsigned short Bs[2][NB*32*64];
  const int tid  = threadIdx.x;
  const int wave = tid >> 6, lane = tid & 63;
  const int l16  = lane & 15, lg = lane >> 4;
  const int f    = blockIdx.x;
  const int xcd  = f & 7, rr = f >> 3;
  const int bx   = xcd*8 + (rr & 7), by = rr >> 3;
  const int m0   = bx * 128, n0 = by * (NB*32);
  const int wm   = (wave & 1) * 64,  wn = (wave >> 1) * (NB*16);

  const f32x4 z4 = {0.f, 0.f, 0.f, 0.f};
  f32x4 acc[4][NB];
#pragma unroll
  for (int i = 0; i < 4; ++i)
#pragma unroll
    for (int j = 0; j < NB; ++j) acc[i][j] = z4;

  const int sr  = lane >> 3;                 // staging row within 8-row chunk
  const int sc8 = ((lane & 7) ^ sr) << 3;    // inverse-swizzled col (elements)
  const unsigned short* Aptr = A + (size_t)m0 * HID;
  const unsigned short* Wptr = W + (size_t)n0 * HID;

  // prologue: stage kt=0 into buffer 0
#pragma unroll
  for (int i = 0; i < 4; ++i) {
    const int c = wave * 4 + i;
    gload_lds16(Aptr + (size_t)(c*8 + sr) * HID + sc8, As[0] + c*512);
  }
#pragma unroll
  for (int i = 0; i < NB; ++i) {
    const int c = wave * NB + i;
    gload_lds16(Wptr + (size_t)(c*8 + sr) * HID + sc8, Bs[0] + c*512);
  }
  __syncthreads();

#pragma unroll 1
  for (int tt = 0; tt < 6; ++tt) {           // 12 K-steps of 64
    GEMM_STEP(0, (2*tt+1)*64, true)
    GEMM_STEP(1, (2*tt+2)*64, (tt < 5))
  }

  // C/D layout (m89-verified): col = lane&15, row = (lane>>4)*4 + j
  if (MODE == 0) {
    unsigned short* out = (unsigned short*)out_raw;
    const float QSCALE = 0.18033688011112042f;  // 0.125 * log2(e) folded into q
    const int which = (n0 + wn) / HID;          // 32-col span never straddles
    if (which == 2) {
      // V: write into swizzled Vt image [bh][tile][d][(slot^ (d&15))*4+j]
      const int e_base = n0 + wn - 2*HID;
#pragma unroll
      for (int nb = 0; nb < NB; ++nb) {
        const int e = e_base + nb*16 + l16;
        const int h = e >> 6, d = e & 63;       // per-element (32-col span safe)
        const float bias = bias2[e];
#pragma unroll
        for (int mb = 0; mb < 4; ++mb) {
          const int m    = m0 + wm + mb*16 + lg*4;
          const int b    = m >> 11, s = m & (SEQ - 1);
          const int tile = s >> 6;
          const int slot = ((s & 63) >> 2) ^ (d & 15);
          ushort4 w;
          w.x = f2bf(acc[mb][nb][0] + bias);
          w.y = f2bf(acc[mb][nb][1] + bias);
          w.z = f2bf(acc[mb][nb][2] + bias);
          w.w = f2bf(acc[mb][nb][3] + bias);
          *(ushort4*)(vtimg + ((((size_t)(b*NHEAD + h)*32 + tile)*64 + d)*64 + slot*4)) = w;
        }
      }
    } else {
      const float* bp  = (which == 0) ? bias0 : bias1;
      const float scl  = (which == 0) ? QSCALE : 1.0f;
      const int e_base = n0 + wn - which*HID;
#pragma unroll
      for (int nb = 0; nb < NB; ++nb) {
        const int e = e_base + nb*16 + l16;
        const float bias = bp[e];
        const int h = e >> 6, d = e & 63;
#pragma unroll
        for (int mb = 0; mb < 4; ++mb)
#pragma unroll
          for (int j = 0; j < 4; ++j) {
            const int m = m0 + wm + mb*16 + lg*4 + j;
            const int b = m >> 11, s = m & (SEQ - 1);
            const float v = (acc[mb][nb][j] + bias) * scl;
            out[((((size_t)which*BSZ + b)*NHEAD + h)*SEQ + s)*DKH + d] = f2bf(v);
          }
      }
    }
  } else {
    float* out = (float*)out_raw;             // d_out is fp32 (reference output dtype)
#pragma unroll
    for (int nb = 0; nb < NB; ++nb) {
      const int n = n0 + wn + nb*16 + l16;
      const float bias = bias0[n];
#pragma unroll
      for (int mb = 0; mb < 4; ++mb)
#pragma unroll
        for (int j = 0; j < 4; ++j) {
          const int m = m0 + wm + mb*16 + lg*4 + j;
          out[(size_t)m*HID + n] = acc[mb][nb][j] + bias;
        }
    }
  }
}

// Flash attention v5 (round-8/11/12 measured best — restored verbatim):
// 1D grid 768 (XCD-major); 4 waves x 32 q-rows; KV tiles of 64, double-
// buffered LDS (K 16B-XOR swizzle; V 8B-XOR swizzled image), loop unrolled
// x2 (compile-time buffer index), hoisted per-lane swizzled bases.
// No max-tracking; row sums via MFMA ones-column.
#define ATTN_STEP(CUR, DOPREF)                                              \
  {                                                                         \
    if (DOPREF) {                                                           \
      gload_lds16(kSrc0, Ks[(CUR)^1] + wave*1024);                          \
      gload_lds16(kSrc1, Ks[(CUR)^1] + wave*1024 + 512);                    \
      gload_lds16(vSrc0, Vs[(CUR)^1] + wave*1024);                          \
      gload_lds16(vSrc1, Vs[(CUR)^1] + wave*1024 + 512);                    \
      kSrc0 += 64*DKH; kSrc1 += 64*DKH; vSrc0 += 4096; vSrc1 += 4096;       \
    }                                                                       \
    const char* kb = (const char*)Ks[CUR];                                  \
    const char* vb = (const char*)Vs[CUR];                                  \
    f32x4 sc[2][4];                                                         \
    __builtin_amdgcn_s_setprio(1);                                          \
    _Pragma("unroll")                                                       \
    for (int nb = 0; nb < 4; ++nb) {                                        \
      bf16x8 kf0 = *(const bf16x8*)(kb + kbase0 + nb*2048);                 \
      bf16x8 kf1 = *(const bf16x8*)(kb + kbase1 + nb*2048);                 \
      f32x4 z0 = z4, z1 = z4;                                               \
      z0 = MFMA16x32(kf0, qf[0][0], z0);                                    \
      z0 = MFMA16x32(kf1, qf[0][1], z0);                                    \
      z1 = MFMA16x32(kf0, qf[1][0], z1);                                    \
      z1 = MFMA16x32(kf1, qf[1][1], z1);                                    \
      sc[0][nb] = z0; sc[1][nb] = z1;                                       \
    }                                                                       \
    __builtin_amdgcn_s_setprio(0);                                          \
    bf16x8 pa[2][2];                                                        \
    _Pragma("unroll")                                                       \
    for (int qa = 0; qa < 2; ++qa)                                          \
      _Pragma("unroll")                                                     \
      for (int nb = 0; nb < 4; ++nb)                                        \
        _Pragma("unroll")                                                   \
        for (int j = 0; j < 4; ++j)                                         \
          pa[qa][nb>>1][(nb&1)*4 + j] =                                     \
            (__bf16)__builtin_amdgcn_exp2f(sc[qa][nb][j]);                  \
    __builtin_amdgcn_s_setprio(1);                                          \
    csum[0] = MFMA16x32(pa[0][0], ones, csum[0]);                           \
    csum[0] = MFMA16x32(pa[0][1], ones, csum[0]);                           \
    csum[1] = MFMA16x32(pa[1][0], ones, csum[1]);                           \
    csum[1] = MFMA16x32(pa[1][1], ones, csum[1]);                           \
    _Pragma("unroll")                                                       \
    for (int db = 0; db < 4; ++db) {                                        \
      bf16x4 v00 = *(const bf16x4*)(vb + vbase0 + db*2048);                 \
      bf16x4 v01 = *(const bf16x4*)(vb + vbase1 + db*2048);                 \
      bf16x4 v10 = *(const bf16x4*)(vb + vbase2 + db*2048);                 \
      bf16x4 v11 = *(const bf16x4*)(vb + vbase3 + db*2048);                 \
      bf16x8 vf0 = __builtin_shufflevector(v00, v01, 0,1,2,3,4,5,6,7);      \
      bf16x8 vf1 = __builtin_shufflevector(v10, v11, 0,1,2,3,4,5,6,7);      \
      cacc[0][db] = MFMA16x32(pa[0][0], vf0, cacc[0][db]);                  \
      cacc[0][db] = MFMA16x32(pa[0][1], vf1, cacc[0][db]);                  \
      cacc[1][db] = MFMA16x32(pa[1][0], vf0, cacc[1][db]);                  \
      cacc[1][db] = MFMA16x32(pa[1][1], vf1, cacc[1][db]);                  \
    }                                                                       \
    __builtin_amdgcn_s_setprio(0);                                          \
    __syncthreads();                                                        \
  }

__global__ __launch_bounds__(256, 3) void attn_kernel(const unsigned short* __restrict__ qkv,
                                                      const unsigned short* __restrict__ vtimg,
                                                      unsigned short* __restrict__ ctx)
{
  __shared__ unsigned short Ks[2][64*64];     // [kc][d]  16B-XOR-swizzled
  __shared__ unsigned short Vs[2][64*64];     // [d][kc]  8B-XOR-swizzled image
  const int tid  = threadIdx.x;
  const int wave = tid >> 6, lane = tid & 63;
  const int l16  = lane & 15, lg = lane >> 4;
  const int f   = blockIdx.x;
  const int xcd = f & 7, idx = f >> 3;        // idx 0..95
  const int bh  = xcd * 6 + (idx >> 4);
  const int qt  = idx & 15;
  const int b   = bh / NHEAD, h = bh - b * NHEAD;
  const int q0  = qt * 128 + wave * 32;

  const unsigned short* Qg = qkv + (size_t)bh * (SEQ*DKH);
  const unsigned short* Kg = qkv + (size_t)(NBH + bh) * (SEQ*DKH);

  const int srow  = lane >> 3;
  const int scolK = ((lane & 7) ^ srow) << 3;
  const unsigned short* kSrc0 = Kg + (size_t)(wave*16 + srow) * DKH + scolK;
  const unsigned short* kSrc1 = Kg + (size_t)(wave*16 + 8 + srow) * DKH + scolK;
  const unsigned short* vSrc0 = vtimg + ((size_t)bh*32*64 + wave*16 + srow) * 64 + (lane & 7) * 8;
  const unsigned short* vSrc1 = vSrc0 + 8*64;

  const int kbase0 = l16*128 + ((lg ^ (l16 & 7)) << 4);
  const int kbase1 = l16*128 + (((lg + 4) ^ (l16 & 7)) << 4);
  const int vbase0 = l16*128 + (((lg     ) ^ l16) << 3);
  const int vbase1 = l16*128 + (((lg +  4) ^ l16) << 3);
  const int vbase2 = l16*128 + (((lg +  8) ^ l16) << 3);
  const int vbase3 = l16*128 + (((lg + 12) ^ l16) << 3);

  bf16x8 qf[2][2];
#pragma unroll
  for (int qa = 0; qa < 2; ++qa) {
    qf[qa][0] = *(const bf16x8*)(Qg + (size_t)(q0 + qa*16 + l16)*DKH + lg*8);
    qf[qa][1] = *(const bf16x8*)(Qg + (size_t)(q0 + qa*16 + l16)*DKH + 32 + lg*8);
  }

  bf16x8 ones;
#pragma unroll
  for (int e = 0; e < 8; ++e) ones[e] = (__bf16)1.0f;

  const f32x4 z4 = {0.f,0.f,0.f,0.f};
  f32x4 cacc[2][4];
  f32x4 csum[2] = {z4, z4};
#pragma unroll
  for (int qa = 0; qa < 2; ++qa)
#pragma unroll
    for (int db = 0; db < 4; ++db) cacc[qa][db] = z4;

  gload_lds16(kSrc0, Ks[0] + wave*1024);
  gload_lds16(kSrc1, Ks[0] + wave*1024 + 512);
  gload_lds16(vSrc0, Vs[0] + wave*1024);
  gload_lds16(vSrc1, Vs[0] + wave*1024 + 512);
  kSrc0 += 64*DKH; kSrc1 += 64*DKH; vSrc0 += 4096; vSrc1 += 4096;
  __syncthreads();

#pragma unroll 1
  for (int tt = 0; tt < 16; ++tt) {
    ATTN_STEP(0, true)
    ATTN_STEP(1, (tt < 15))
  }

#pragma unroll
  for (int qa = 0; qa < 2; ++qa) {
    f32x4 inv;
#pragma unroll
    for (int j = 0; j < 4; ++j) inv[j] = 1.0f / csum[qa][j];
#pragma unroll
    for (int db = 0; db < 4; ++db)
#pragma unroll
      for (int j = 0; j < 4; ++j) {
        const int srow2 = q0 + qa*16 + lg*4 + j;
        ctx[((size_t)(b*SEQ + srow2))*HID + h*DKH + db*16 + l16] = f2bf(cacc[qa][db][j] * inv[j]);
      }
  }
}

extern "C" void kernel_launch(void* const* d_in, const int* in_sizes, int n_in,
                              void* d_out, int out_size, void* d_ws, size_t ws_size,
                              hipStream_t stream) {
  (void)in_sizes; (void)n_in; (void)out_size; (void)ws_size;
  const float* x  = (const float*)d_in[0];
  const float* Wq = (const float*)d_in[1];
  const float* bq = (const float*)d_in[2];
  const float* Wk = (const float*)d_in[3];
  const float* bk = (const float*)d_in[4];
  const float* Wv = (const float*)d_in[5];
  const float* bv = (const float*)d_in[6];
  const float* Wo = (const float*)d_in[7];
  const float* bo = (const float*)d_in[8];

  // workspace layout (bf16 elements): ~55 MB total
  unsigned short* ws   = (unsigned short*)d_ws;
  unsigned short* Xb   = ws;                                   // [8192][768]
  unsigned short* Wqkv = Xb + (size_t)MTOT * HID;              // [2304][768]
  unsigned short* Wob  = Wqkv + (size_t)3 * HID * HID;         // [768][768]
  unsigned short* qkvb = Wob + (size_t)HID * HID;              // [2][48][2048][64] (q,k only)
  unsigned short* vtb  = qkvb + (size_t)2 * NBH * SEQ * DKH;   // [48][32][64][64] swizzled V image
  unsigned short* ctxb = Xb;                                   // reuse after QKV GEMM

  cvtall_kernel<<<6144 + 4*576, 256, 0, stream>>>(x, Wq, Wk, Wv, Wo, Xb, Wqkv);

  gemm_kernel<0,2><<<2304, 256, 0, stream>>>(Xb, Wqkv, bq, bk, bv, qkvb, vtb);
  attn_kernel<<<768, 256, 0, stream>>>(qkvb, vtb, ctxb);
  gemm_kernel<1,2><<<768, 256, 0, stream>>>(ctxb, Wob, bo, nullptr, nullptr, d_out, nullptr);
}